// Round 3
// baseline (472.795 us; speedup 1.0000x reference)
//
#include <hip/hip_runtime.h>
#include <hip/hip_bf16.h>
#include <stdint.h>

typedef short bf16x8 __attribute__((ext_vector_type(8)));
typedef short bf16x4 __attribute__((ext_vector_type(4)));
typedef float f32x4 __attribute__((ext_vector_type(4)));

#define BHC 64     // B*H
#define NQ 2048    // sequence length
#define DD 64      // head dim
#define NE 192     // 3*D
#define PLP 40     // pbuf row stride (shorts): 80B rows, 16B-aligned, bank-clean
// Q pre-scale: (1/8) * log2(e) -> softmax via exp2
#define QSCALE 0.1803368801111245f

__device__ __forceinline__ short f2bf(float f) {
  unsigned u = __float_as_uint(f);
  unsigned r = (u + 0x7FFFu + ((u >> 16) & 1u)) >> 16;
  return (short)r;
}

__device__ __forceinline__ bf16x8 pack8(float4 a, float4 b) {
  bf16x8 v;
  v[0] = f2bf(a.x); v[1] = f2bf(a.y); v[2] = f2bf(a.z); v[3] = f2bf(a.w);
  v[4] = f2bf(b.x); v[5] = f2bf(b.y); v[6] = f2bf(b.z); v[7] = f2bf(b.w);
  return v;
}

__device__ __forceinline__ short2 pk_bf16(float a, float b) {
  __hip_bfloat162 c = __float22bfloat162_rn(make_float2(a, b));
  return *reinterpret_cast<short2*>(&c);
}

// ---------------------------------------------------------------------------
// Kernel 0: one-time weight prep (unchanged). Permutes w into bf16 MFMA
// fragment order wp[h][chunk(24)][lane][8] and bias into biasp[h][wh][dd].
// ---------------------------------------------------------------------------
__global__ __launch_bounds__(256) void wprep_kernel(
    const float* __restrict__ w, const float* __restrict__ bq,
    short* __restrict__ wp, float* __restrict__ biasp) {
  const int h = blockIdx.y;
  const int r = blockIdx.x * 256 + threadIdx.x;   // 0..12287
  const int j = r & 7;
  const int t = r >> 3;
  const int quad = t & 3, col = (t >> 2) & 15;
  const int kc = (t >> 6) & 1, ntb = (t >> 7) & 3, wh = t >> 9;
  const int d = kc * 32 + quad * 8 + j;           // K index (input dim)
  const int e = (ntb * 16 + col) * 3 + wh;        // interleaved output col
  wp[h * 12288 + r] = f2bf(w[((size_t)h * DD + d) * NE + e]);
  if (r < 192) {
    const int wh2 = r / 64, c = r - wh2 * 64;
    biasp[h * 192 + r] = bq[h * NE + c * 3 + wh2];  // biasp[h][wh][dd]
  }
}

// ---------------------------------------------------------------------------
// Kernel 1: QKV projection (byte-identical to R2 for attribution; its
// counters should surface in the next round's top-5 once attn < ~85us).
// ---------------------------------------------------------------------------
__global__ __launch_bounds__(256) void proj_kernel(
    const float* __restrict__ x, const short* __restrict__ wp,
    const float* __restrict__ biasp, short* __restrict__ Qg,
    short* __restrict__ Kg, short* __restrict__ Vtg) {
  __shared__ short sV[4][64 * 72];      // per-wave V staging [d][row(64) pad 72]

  const int tid = threadIdx.x;
  const int bh = blockIdx.x >> 3;       // 8 row-blocks of 256 per bh
  const int rb = blockIdx.x & 7;
  const int h = bh & 15;
  const int wave = tid >> 6;
  const int lane = tid & 63;
  const int col = lane & 15, quad = lane >> 4;
  const int wbase = rb * 256 + wave * 64;   // this wave's 64 rows

  // --- hold all 24 w fragments in registers (one parallel burst) ---
  const short* wph = wp + h * 12288;
  const int fo = (col * 4 + quad) * 8;
  bf16x8 wf[24];
#pragma unroll
  for (int i = 0; i < 24; ++i) wf[i] = *(const bf16x8*)(wph + i * 512 + fo);

  const float* bph = biasp + h * 192;
  const float* xb = x + ((size_t)bh * NQ + wbase + col) * DD;
  short* sVw = sV[wave];

  // prologue: x fragment for tile 0
  bf16x8 aqc[2];
#pragma unroll
  for (int kc = 0; kc < 2; ++kc) {
    const float4* p4 = (const float4*)(xb + kc * 32 + quad * 8);
    aqc[kc] = pack8(p4[0], p4[1]);
  }

#pragma unroll
  for (int r = 0; r < 4; ++r) {
    // issue next tile's x loads early (raw float4, in flight during MFMAs)
    float4 nx0, nx1, nx2, nx3;
    if (r < 3) {
      const float* xn = xb + (size_t)(r + 1) * 16 * DD;
      nx0 = *(const float4*)(xn + quad * 8);
      nx1 = *(const float4*)(xn + quad * 8 + 4);
      nx2 = *(const float4*)(xn + 32 + quad * 8);
      nx3 = *(const float4*)(xn + 32 + quad * 8 + 4);
    }

    // acc init = bias (broadcast L1-hot loads); (xw+b) computed directly
    f32x4 acc[12];
#pragma unroll
    for (int nt = 0; nt < 12; ++nt)
      acc[nt] = *(const f32x4*)(bph + (nt >> 2) * 64 + (nt & 3) * 16 + quad * 4);

#pragma unroll
    for (int nt = 0; nt < 12; ++nt) {
      acc[nt] = __builtin_amdgcn_mfma_f32_16x16x32_bf16(wf[nt * 2 + 0], aqc[0], acc[nt], 0, 0, 0);
      acc[nt] = __builtin_amdgcn_mfma_f32_16x16x32_bf16(wf[nt * 2 + 1], aqc[1], acc[nt], 0, 0, 0);
    }

    // epilogue: lane holds out[row = wbase + r*16 + col][dd = ntb*16+quad*4+i]
    short* Qp = Qg + ((size_t)bh * NQ + wbase + r * 16 + col) * DD;
    short* Kp = Kg + ((size_t)bh * NQ + wbase + r * 16 + col) * DD;
#pragma unroll
    for (int nt = 0; nt < 12; ++nt) {
      const int ntb = nt & 3;
      float v0 = acc[nt][0], v1 = acc[nt][1], v2 = acc[nt][2], v3 = acc[nt][3];
      if (nt < 4) { v0 *= QSCALE; v1 *= QSCALE; v2 *= QSCALE; v3 *= QSCALE; }
      if (nt < 8) {
        short2 s01 = pk_bf16(v0, v1);
        short2 s23 = pk_bf16(v2, v3);
        bf16x4 pv; pv[0] = s01.x; pv[1] = s01.y; pv[2] = s23.x; pv[3] = s23.y;
        short* P = (nt < 4) ? Qp : Kp;
        *(bf16x4*)(P + ntb * 16 + quad * 4) = pv;
      } else {
        const int dd = ntb * 16 + quad * 4;
        const int rc = r * 16 + col;
        sVw[(dd + 0) * 72 + rc] = f2bf(v0);
        sVw[(dd + 1) * 72 + rc] = f2bf(v1);
        sVw[(dd + 2) * 72 + rc] = f2bf(v2);
        sVw[(dd + 3) * 72 + rc] = f2bf(v3);
      }
    }

    // convert prefetched x for next tile
    if (r < 3) {
      aqc[0] = pack8(nx0, nx1);
      aqc[1] = pack8(nx2, nx3);
    }
  }

  // V^T flush: 8 lanes per d-row -> full 128B-line global writes
  short* Vp = Vtg + (size_t)bh * DD * NQ + wbase;
  const int dl = lane >> 3, ro = (lane & 7) * 8;
#pragma unroll
  for (int g = 0; g < 8; ++g) {
    const int d = g * 8 + dl;
    *(bf16x8*)(Vp + (size_t)d * NQ + ro) = *(const bf16x8*)(sVw + d * 72 + ro);
  }
}

// ---------------------------------------------------------------------------
// Kernel 2: flash attention v3. Same proven 16x16 fragment layouts; change:
// PV split into two 32-key halves interleaved with the S halves.
//  - pbuf [4][64][40]: 80B rows (16B-aligned b128), bank-clean (worst 2-way,
//    free) -> kills the 8-way ap-read conflicts of LDP=72 (6.29M cycles).
//  - LDS 69.6KB -> 53.2KB -> 3 blocks/CU (was 2). __launch_bounds__(256,3).
//  - V fragments hoisted per half: 8 LDS V-reads/tile (was 32; pbuf aliasing
//    blocked CSE before).
//  - S-half-B MFMAs overlap PV-half-A LDS reads (shorter P dep chain).
// ---------------------------------------------------------------------------
__global__ __launch_bounds__(256, 3) void attn_kernel(
    const short* __restrict__ Qg, const short* __restrict__ Kg,
    const short* __restrict__ Vtg, float* __restrict__ out) {
  __shared__ short kbuf[2][64 * 64];    // K tile  [key][d], XOR-swizzled
  __shared__ short vbuf[2][64 * 64];    // V^T tile [d][key], XOR-swizzled
  __shared__ short pbuf[4][64 * PLP];   // per-wave P half-tile [q][key(32)]

  const int tid = threadIdx.x;
  const int bh = blockIdx.x & 63;       // XCD-local: head pinned to blk%8's XCD
  const int qb = blockIdx.x >> 6;       // 8 q-blocks of 256 per head
  const int wave = tid >> 6, lane = tid & 63;
  const int col = lane & 15, quad = lane >> 4;
  const int qbase = qb * 256 + wave * 64;

  // Q fragments (B-operand for S^T): B[n=q][k=d], persistent in VGPRs
  bf16x8 bqf[4][2];
#pragma unroll
  for (int ntq = 0; ntq < 4; ++ntq)
#pragma unroll
    for (int kc = 0; kc < 2; ++kc)
      bqf[ntq][kc] = *(const bf16x8*)(Qg + ((size_t)bh * NQ + qbase + ntq * 16 + col) * DD +
                                      kc * 32 + quad * 8);

  f32x4 o[4][4];
  float l_acc[4];
#pragma unroll
  for (int mtq = 0; mtq < 4; ++mtq) {
    l_acc[mtq] = 0.f;
#pragma unroll
    for (int ntd = 0; ntd < 4; ++ntd) o[mtq][ntd] = (f32x4){0.f, 0.f, 0.f, 0.f};
  }

  short* pb = pbuf[wave];
  const short* Kb = Kg + (size_t)bh * NQ * DD;
  const short* Vb = Vtg + (size_t)bh * DD * NQ;

  // staging: 2 K-chunks + 2 V-chunks of 16B per thread; dst chunk ^= row&7
  const int r0 = tid >> 3, c0 = tid & 7;
  const int dst0 = r0 * 64 + ((c0 ^ (r0 & 7)) * 8);
  const int dst1 = (r0 + 32) * 64 + ((c0 ^ (r0 & 7)) * 8);  // (r0+32)&7 == r0&7
  const int src0 = r0 * DD + c0 * 8;
  const size_t vsrc0o = (size_t)r0 * NQ + c0 * 8;
  const size_t vsrc1o = (size_t)(r0 + 32) * NQ + c0 * 8;

  // prologue: stage tile 0 into buffer 0
  {
    bf16x8 k0 = *(const bf16x8*)(Kb + src0);
    bf16x8 k1 = *(const bf16x8*)(Kb + src0 + 32 * DD);
    bf16x8 v0 = *(const bf16x8*)(Vb + vsrc0o);
    bf16x8 v1 = *(const bf16x8*)(Vb + vsrc1o);
    *(bf16x8*)(&kbuf[0][dst0]) = k0;
    *(bf16x8*)(&kbuf[0][dst1]) = k1;
    *(bf16x8*)(&vbuf[0][dst0]) = v0;
    *(bf16x8*)(&vbuf[0][dst1]) = v1;
  }
  __syncthreads();

#pragma unroll 1
  for (int t = 0; t < 32; ++t) {
    const int p = t & 1;
    const short* kb = kbuf[p];
    const short* vb_s = vbuf[p];

    // prefetch next tile into regs (4 x bf16x8 = 16 VGPRs; in flight during compute)
    bf16x8 nk0, nk1, nv0, nv1;
    if (t < 31) {
      const short* Kn = Kb + (t + 1) * 64 * DD;
      const short* Vn = Vb + (t + 1) * 64;
      nk0 = *(const bf16x8*)(Kn + src0);
      nk1 = *(const bf16x8*)(Kn + src0 + 32 * DD);
      nv0 = *(const bf16x8*)(Vn + vsrc0o);
      nv1 = *(const bf16x8*)(Vn + vsrc1o);
    }

#pragma unroll
    for (int hf = 0; hf < 2; ++hf) {
      // ---- S^T half: keys hf*32 .. hf*32+31, exp2, b64 P-writes ----
#pragma unroll
      for (int m2 = 0; m2 < 2; ++m2) {
        const int mtk = hf * 2 + m2;
        const int krow = mtk * 16 + col;
        const int kx = krow & 7;
        bf16x8 ka0 = *(const bf16x8*)(&kb[krow * 64 + ((quad ^ kx) * 8)]);
        bf16x8 ka1 = *(const bf16x8*)(&kb[krow * 64 + (((4 + quad) ^ kx) * 8)]);
#pragma unroll
        for (int ntq = 0; ntq < 4; ++ntq) {
          f32x4 s = (f32x4){0.f, 0.f, 0.f, 0.f};
          s = __builtin_amdgcn_mfma_f32_16x16x32_bf16(ka0, bqf[ntq][0], s, 0, 0, 0);
          s = __builtin_amdgcn_mfma_f32_16x16x32_bf16(ka1, bqf[ntq][1], s, 0, 0, 0);
          // lane holds S^T[key=mtk*16+quad*4+r][q=ntq*16+col]
          float p0 = __builtin_amdgcn_exp2f(s[0]);
          float p1 = __builtin_amdgcn_exp2f(s[1]);
          float p2 = __builtin_amdgcn_exp2f(s[2]);
          float p3 = __builtin_amdgcn_exp2f(s[3]);
          l_acc[ntq] += (p0 + p1) + (p2 + p3);
          short2 s01 = pk_bf16(p0, p1);
          short2 s23 = pk_bf16(p2, p3);
          bf16x4 pv; pv[0] = s01.x; pv[1] = s01.y; pv[2] = s23.x; pv[3] = s23.y;
          *(bf16x4*)(&pb[(ntq * 16 + col) * PLP + m2 * 16 + quad * 4]) = pv;
        }
      }

      // ---- O += P*V for this 32-key half (hoisted V frags, 16 MFMAs) ----
      bf16x8 vf[4];
#pragma unroll
      for (int ntd = 0; ntd < 4; ++ntd) {
        const int vrow = ntd * 16 + col;
        const int vx = vrow & 7;
        vf[ntd] = *(const bf16x8*)(&vb_s[vrow * 64 + (((hf * 4 + quad) ^ vx) * 8)]);
      }
#pragma unroll
      for (int mtq = 0; mtq < 4; ++mtq) {
        bf16x8 ap = *(const bf16x8*)(&pb[(mtq * 16 + col) * PLP + quad * 8]);
#pragma unroll
        for (int ntd = 0; ntd < 4; ++ntd)
          o[mtq][ntd] = __builtin_amdgcn_mfma_f32_16x16x32_bf16(ap, vf[ntd], o[mtq][ntd], 0, 0, 0);
      }
    }

    // write prefetched tile into the other buffer, single barrier
    if (t < 31) {
      short* kn = kbuf[1 - p];
      short* vn = vbuf[1 - p];
      *(bf16x8*)(&kn[dst0]) = nk0;
      *(bf16x8*)(&kn[dst1]) = nk1;
      *(bf16x8*)(&vn[dst0]) = nv0;
      *(bf16x8*)(&vn[dst1]) = nv1;
      __syncthreads();
    }
  }

  // epilogue: reduce l across quads, normalize, store fp32 (R4-proven)
#pragma unroll
  for (int mtq = 0; mtq < 4; ++mtq) {
    float l = l_acc[mtq];
    l += __shfl_xor(l, 16);
    l += __shfl_xor(l, 32);   // lane now has total l for q = mtq*16 + col
#pragma unroll
    for (int r = 0; r < 4; ++r) {
      float inv = 1.0f / __shfl(l, quad * 4 + r);
      int rq = qbase + mtq * 16 + quad * 4 + r;
      float* orow = out + ((size_t)bh * NQ + rq) * DD;
#pragma unroll
      for (int ntd = 0; ntd < 4; ++ntd) orow[ntd * 16 + col] = o[mtq][ntd][r] * inv;
    }
  }
}

extern "C" void kernel_launch(void* const* d_in, const int* in_sizes, int n_in,
                              void* d_out, int out_size, void* d_ws, size_t ws_size,
                              hipStream_t stream) {
  const float* x = (const float*)d_in[0];    // [4,16,2048,64] fp32
  const float* w = (const float*)d_in[1];    // [16,64,192] fp32
  const float* bq = (const float*)d_in[2];   // [16,1,192] fp32
  float* out = (float*)d_out;                // [4,16,2048,64] fp32

  short* Qg = (short*)d_ws;                          // bf16 [64][2048][64], pre-scaled
  short* Kg = Qg + (size_t)BHC * NQ * DD;            // bf16 [64][2048][64]
  short* Vtg = Kg + (size_t)BHC * NQ * DD;           // bf16 [64][64][2048]
  short* wp = Vtg + (size_t)BHC * DD * NQ;           // bf16 [16][12288] fragment-ordered
  float* biasp = (float*)(wp + 16 * 12288);          // fp32 [16][192] permuted

  wprep_kernel<<<dim3(48, 16), dim3(256), 0, stream>>>(w, bq, wp, biasp);
  proj_kernel<<<dim3(512), dim3(256), 0, stream>>>(x, wp, biasp, Qg, Kg, Vtg);
  attn_kernel<<<dim3(512), dim3(256), 0, stream>>>(Qg, Kg, Vtg, out);
}

// Round 4
// 179.085 us; speedup vs baseline: 2.6401x; 2.6401x over previous
//
#include <hip/hip_runtime.h>
#include <hip/hip_bf16.h>
#include <stdint.h>

typedef short bf16x8 __attribute__((ext_vector_type(8)));
typedef short bf16x4 __attribute__((ext_vector_type(4)));
typedef float f32x4 __attribute__((ext_vector_type(4)));

#define BHC 64     // B*H
#define NQ 2048    // sequence length
#define DD 64      // head dim
#define NE 192     // 3*D
#define PLP 40     // pbuf row stride (shorts): 80B rows, 16B-aligned
// Q pre-scale: (1/8) * log2(e) -> softmax via exp2
#define QSCALE 0.1803368801111245f

__device__ __forceinline__ short f2bf(float f) {
  unsigned u = __float_as_uint(f);
  unsigned r = (u + 0x7FFFu + ((u >> 16) & 1u)) >> 16;
  return (short)r;
}

__device__ __forceinline__ bf16x8 pack8(float4 a, float4 b) {
  bf16x8 v;
  v[0] = f2bf(a.x); v[1] = f2bf(a.y); v[2] = f2bf(a.z); v[3] = f2bf(a.w);
  v[4] = f2bf(b.x); v[5] = f2bf(b.y); v[6] = f2bf(b.z); v[7] = f2bf(b.w);
  return v;
}

__device__ __forceinline__ short2 pk_bf16(float a, float b) {
  __hip_bfloat162 c = __float22bfloat162_rn(make_float2(a, b));
  return *reinterpret_cast<short2*>(&c);
}

// ---------------------------------------------------------------------------
// Kernel 0: one-time weight prep (unchanged). Permutes w into bf16 MFMA
// fragment order wp[h][chunk(24)][lane][8] and bias into biasp[h][wh][dd].
// ---------------------------------------------------------------------------
__global__ __launch_bounds__(256) void wprep_kernel(
    const float* __restrict__ w, const float* __restrict__ bq,
    short* __restrict__ wp, float* __restrict__ biasp) {
  const int h = blockIdx.y;
  const int r = blockIdx.x * 256 + threadIdx.x;   // 0..12287
  const int j = r & 7;
  const int t = r >> 3;
  const int quad = t & 3, col = (t >> 2) & 15;
  const int kc = (t >> 6) & 1, ntb = (t >> 7) & 3, wh = t >> 9;
  const int d = kc * 32 + quad * 8 + j;           // K index (input dim)
  const int e = (ntb * 16 + col) * 3 + wh;        // interleaved output col
  wp[h * 12288 + r] = f2bf(w[((size_t)h * DD + d) * NE + e]);
  if (r < 192) {
    const int wh2 = r / 64, c = r - wh2 * 64;
    biasp[h * 192 + r] = bq[h * NE + c * 3 + wh2];  // biasp[h][wh][dd]
  }
}

// ---------------------------------------------------------------------------
// Kernel 1: QKV projection (byte-identical to R2/R3 for attribution).
// ---------------------------------------------------------------------------
__global__ __launch_bounds__(256) void proj_kernel(
    const float* __restrict__ x, const short* __restrict__ wp,
    const float* __restrict__ biasp, short* __restrict__ Qg,
    short* __restrict__ Kg, short* __restrict__ Vtg) {
  __shared__ short sV[4][64 * 72];      // per-wave V staging [d][row(64) pad 72]

  const int tid = threadIdx.x;
  const int bh = blockIdx.x >> 3;       // 8 row-blocks of 256 per bh
  const int rb = blockIdx.x & 7;
  const int h = bh & 15;
  const int wave = tid >> 6;
  const int lane = tid & 63;
  const int col = lane & 15, quad = lane >> 4;
  const int wbase = rb * 256 + wave * 64;   // this wave's 64 rows

  // --- hold all 24 w fragments in registers (one parallel burst) ---
  const short* wph = wp + h * 12288;
  const int fo = (col * 4 + quad) * 8;
  bf16x8 wf[24];
#pragma unroll
  for (int i = 0; i < 24; ++i) wf[i] = *(const bf16x8*)(wph + i * 512 + fo);

  const float* bph = biasp + h * 192;
  const float* xb = x + ((size_t)bh * NQ + wbase + col) * DD;
  short* sVw = sV[wave];

  // prologue: x fragment for tile 0
  bf16x8 aqc[2];
#pragma unroll
  for (int kc = 0; kc < 2; ++kc) {
    const float4* p4 = (const float4*)(xb + kc * 32 + quad * 8);
    aqc[kc] = pack8(p4[0], p4[1]);
  }

#pragma unroll
  for (int r = 0; r < 4; ++r) {
    // issue next tile's x loads early (raw float4, in flight during MFMAs)
    float4 nx0, nx1, nx2, nx3;
    if (r < 3) {
      const float* xn = xb + (size_t)(r + 1) * 16 * DD;
      nx0 = *(const float4*)(xn + quad * 8);
      nx1 = *(const float4*)(xn + quad * 8 + 4);
      nx2 = *(const float4*)(xn + 32 + quad * 8);
      nx3 = *(const float4*)(xn + 32 + quad * 8 + 4);
    }

    // acc init = bias (broadcast L1-hot loads); (xw+b) computed directly
    f32x4 acc[12];
#pragma unroll
    for (int nt = 0; nt < 12; ++nt)
      acc[nt] = *(const f32x4*)(bph + (nt >> 2) * 64 + (nt & 3) * 16 + quad * 4);

#pragma unroll
    for (int nt = 0; nt < 12; ++nt) {
      acc[nt] = __builtin_amdgcn_mfma_f32_16x16x32_bf16(wf[nt * 2 + 0], aqc[0], acc[nt], 0, 0, 0);
      acc[nt] = __builtin_amdgcn_mfma_f32_16x16x32_bf16(wf[nt * 2 + 1], aqc[1], acc[nt], 0, 0, 0);
    }

    // epilogue: lane holds out[row = wbase + r*16 + col][dd = ntb*16+quad*4+i]
    short* Qp = Qg + ((size_t)bh * NQ + wbase + r * 16 + col) * DD;
    short* Kp = Kg + ((size_t)bh * NQ + wbase + r * 16 + col) * DD;
#pragma unroll
    for (int nt = 0; nt < 12; ++nt) {
      const int ntb = nt & 3;
      float v0 = acc[nt][0], v1 = acc[nt][1], v2 = acc[nt][2], v3 = acc[nt][3];
      if (nt < 4) { v0 *= QSCALE; v1 *= QSCALE; v2 *= QSCALE; v3 *= QSCALE; }
      if (nt < 8) {
        short2 s01 = pk_bf16(v0, v1);
        short2 s23 = pk_bf16(v2, v3);
        bf16x4 pv; pv[0] = s01.x; pv[1] = s01.y; pv[2] = s23.x; pv[3] = s23.y;
        short* P = (nt < 4) ? Qp : Kp;
        *(bf16x4*)(P + ntb * 16 + quad * 4) = pv;
      } else {
        const int dd = ntb * 16 + quad * 4;
        const int rc = r * 16 + col;
        sVw[(dd + 0) * 72 + rc] = f2bf(v0);
        sVw[(dd + 1) * 72 + rc] = f2bf(v1);
        sVw[(dd + 2) * 72 + rc] = f2bf(v2);
        sVw[(dd + 3) * 72 + rc] = f2bf(v3);
      }
    }

    // convert prefetched x for next tile
    if (r < 3) {
      aqc[0] = pack8(nx0, nx1);
      aqc[1] = pack8(nx2, nx3);
    }
  }

  // V^T flush: 8 lanes per d-row -> full 128B-line global writes
  short* Vp = Vtg + (size_t)bh * DD * NQ + wbase;
  const int dl = lane >> 3, ro = (lane & 7) * 8;
#pragma unroll
  for (int g = 0; g < 8; ++g) {
    const int d = g * 8 + dl;
    *(bf16x8*)(Vp + (size_t)d * NQ + ro) = *(const bf16x8*)(sVw + d * 72 + ro);
  }
}

// ---------------------------------------------------------------------------
// Kernel 2: flash attention v3b. Identical to R3's v3 EXCEPT launch_bounds
// min-waves 3 -> 2: on gfx950 the unified VGPR+AGPR file means 3 waves/EU
// caps total regs at ~170; this kernel needs ~190 (124V + 64A) -> R3 spilled
// o[][] to scratch (FETCH 27MB->707MB, 4.3x regression). (256,2) restores
// the no-spill allocation while keeping the 53.2KB LDS (v3 pbuf+PV-split).
// ---------------------------------------------------------------------------
__global__ __launch_bounds__(256, 2) void attn_kernel(
    const short* __restrict__ Qg, const short* __restrict__ Kg,
    const short* __restrict__ Vtg, float* __restrict__ out) {
  __shared__ short kbuf[2][64 * 64];    // K tile  [key][d], XOR-swizzled
  __shared__ short vbuf[2][64 * 64];    // V^T tile [d][key], XOR-swizzled
  __shared__ short pbuf[4][64 * PLP];   // per-wave P half-tile [q][key(32)]

  const int tid = threadIdx.x;
  const int bh = blockIdx.x & 63;       // XCD-local: head pinned to blk%8's XCD
  const int qb = blockIdx.x >> 6;       // 8 q-blocks of 256 per head
  const int wave = tid >> 6, lane = tid & 63;
  const int col = lane & 15, quad = lane >> 4;
  const int qbase = qb * 256 + wave * 64;

  // Q fragments (B-operand for S^T): B[n=q][k=d], persistent in VGPRs
  bf16x8 bqf[4][2];
#pragma unroll
  for (int ntq = 0; ntq < 4; ++ntq)
#pragma unroll
    for (int kc = 0; kc < 2; ++kc)
      bqf[ntq][kc] = *(const bf16x8*)(Qg + ((size_t)bh * NQ + qbase + ntq * 16 + col) * DD +
                                      kc * 32 + quad * 8);

  f32x4 o[4][4];
  float l_acc[4];
#pragma unroll
  for (int mtq = 0; mtq < 4; ++mtq) {
    l_acc[mtq] = 0.f;
#pragma unroll
    for (int ntd = 0; ntd < 4; ++ntd) o[mtq][ntd] = (f32x4){0.f, 0.f, 0.f, 0.f};
  }

  short* pb = pbuf[wave];
  const short* Kb = Kg + (size_t)bh * NQ * DD;
  const short* Vb = Vtg + (size_t)bh * DD * NQ;

  // staging: 2 K-chunks + 2 V-chunks of 16B per thread; dst chunk ^= row&7
  const int r0 = tid >> 3, c0 = tid & 7;
  const int dst0 = r0 * 64 + ((c0 ^ (r0 & 7)) * 8);
  const int dst1 = (r0 + 32) * 64 + ((c0 ^ (r0 & 7)) * 8);  // (r0+32)&7 == r0&7
  const int src0 = r0 * DD + c0 * 8;
  const size_t vsrc0o = (size_t)r0 * NQ + c0 * 8;
  const size_t vsrc1o = (size_t)(r0 + 32) * NQ + c0 * 8;

  // prologue: stage tile 0 into buffer 0
  {
    bf16x8 k0 = *(const bf16x8*)(Kb + src0);
    bf16x8 k1 = *(const bf16x8*)(Kb + src0 + 32 * DD);
    bf16x8 v0 = *(const bf16x8*)(Vb + vsrc0o);
    bf16x8 v1 = *(const bf16x8*)(Vb + vsrc1o);
    *(bf16x8*)(&kbuf[0][dst0]) = k0;
    *(bf16x8*)(&kbuf[0][dst1]) = k1;
    *(bf16x8*)(&vbuf[0][dst0]) = v0;
    *(bf16x8*)(&vbuf[0][dst1]) = v1;
  }
  __syncthreads();

#pragma unroll 1
  for (int t = 0; t < 32; ++t) {
    const int p = t & 1;
    const short* kb = kbuf[p];
    const short* vb_s = vbuf[p];

    // prefetch next tile into regs (4 x bf16x8 = 16 VGPRs; in flight during compute)
    bf16x8 nk0, nk1, nv0, nv1;
    if (t < 31) {
      const short* Kn = Kb + (t + 1) * 64 * DD;
      const short* Vn = Vb + (t + 1) * 64;
      nk0 = *(const bf16x8*)(Kn + src0);
      nk1 = *(const bf16x8*)(Kn + src0 + 32 * DD);
      nv0 = *(const bf16x8*)(Vn + vsrc0o);
      nv1 = *(const bf16x8*)(Vn + vsrc1o);
    }

#pragma unroll
    for (int hf = 0; hf < 2; ++hf) {
      // ---- S^T half: keys hf*32 .. hf*32+31, exp2, b64 P-writes ----
#pragma unroll
      for (int m2 = 0; m2 < 2; ++m2) {
        const int mtk = hf * 2 + m2;
        const int krow = mtk * 16 + col;
        const int kx = krow & 7;
        bf16x8 ka0 = *(const bf16x8*)(&kb[krow * 64 + ((quad ^ kx) * 8)]);
        bf16x8 ka1 = *(const bf16x8*)(&kb[krow * 64 + (((4 + quad) ^ kx) * 8)]);
#pragma unroll
        for (int ntq = 0; ntq < 4; ++ntq) {
          f32x4 s = (f32x4){0.f, 0.f, 0.f, 0.f};
          s = __builtin_amdgcn_mfma_f32_16x16x32_bf16(ka0, bqf[ntq][0], s, 0, 0, 0);
          s = __builtin_amdgcn_mfma_f32_16x16x32_bf16(ka1, bqf[ntq][1], s, 0, 0, 0);
          // lane holds S^T[key=mtk*16+quad*4+r][q=ntq*16+col]
          float p0 = __builtin_amdgcn_exp2f(s[0]);
          float p1 = __builtin_amdgcn_exp2f(s[1]);
          float p2 = __builtin_amdgcn_exp2f(s[2]);
          float p3 = __builtin_amdgcn_exp2f(s[3]);
          l_acc[ntq] += (p0 + p1) + (p2 + p3);
          short2 s01 = pk_bf16(p0, p1);
          short2 s23 = pk_bf16(p2, p3);
          bf16x4 pv; pv[0] = s01.x; pv[1] = s01.y; pv[2] = s23.x; pv[3] = s23.y;
          *(bf16x4*)(&pb[(ntq * 16 + col) * PLP + m2 * 16 + quad * 4]) = pv;
        }
      }

      // ---- O += P*V for this 32-key half (hoisted V frags, 16 MFMAs) ----
      bf16x8 vf[4];
#pragma unroll
      for (int ntd = 0; ntd < 4; ++ntd) {
        const int vrow = ntd * 16 + col;
        const int vx = vrow & 7;
        vf[ntd] = *(const bf16x8*)(&vb_s[vrow * 64 + (((hf * 4 + quad) ^ vx) * 8)]);
      }
#pragma unroll
      for (int mtq = 0; mtq < 4; ++mtq) {
        bf16x8 ap = *(const bf16x8*)(&pb[(mtq * 16 + col) * PLP + quad * 8]);
#pragma unroll
        for (int ntd = 0; ntd < 4; ++ntd)
          o[mtq][ntd] = __builtin_amdgcn_mfma_f32_16x16x32_bf16(ap, vf[ntd], o[mtq][ntd], 0, 0, 0);
      }
    }

    // write prefetched tile into the other buffer, single barrier
    if (t < 31) {
      short* kn = kbuf[1 - p];
      short* vn = vbuf[1 - p];
      *(bf16x8*)(&kn[dst0]) = nk0;
      *(bf16x8*)(&kn[dst1]) = nk1;
      *(bf16x8*)(&vn[dst0]) = nv0;
      *(bf16x8*)(&vn[dst1]) = nv1;
      __syncthreads();
    }
  }

  // epilogue: reduce l across quads, normalize, store fp32 (R4-proven)
#pragma unroll
  for (int mtq = 0; mtq < 4; ++mtq) {
    float l = l_acc[mtq];
    l += __shfl_xor(l, 16);
    l += __shfl_xor(l, 32);   // lane now has total l for q = mtq*16 + col
#pragma unroll
    for (int r = 0; r < 4; ++r) {
      float inv = 1.0f / __shfl(l, quad * 4 + r);
      int rq = qbase + mtq * 16 + quad * 4 + r;
      float* orow = out + ((size_t)bh * NQ + rq) * DD;
#pragma unroll
      for (int ntd = 0; ntd < 4; ++ntd) orow[ntd * 16 + col] = o[mtq][ntd][r] * inv;
    }
  }
}

extern "C" void kernel_launch(void* const* d_in, const int* in_sizes, int n_in,
                              void* d_out, int out_size, void* d_ws, size_t ws_size,
                              hipStream_t stream) {
  const float* x = (const float*)d_in[0];    // [4,16,2048,64] fp32
  const float* w = (const float*)d_in[1];    // [16,64,192] fp32
  const float* bq = (const float*)d_in[2];   // [16,1,192] fp32
  float* out = (float*)d_out;                // [4,16,2048,64] fp32

  short* Qg = (short*)d_ws;                          // bf16 [64][2048][64], pre-scaled
  short* Kg = Qg + (size_t)BHC * NQ * DD;            // bf16 [64][2048][64]
  short* Vtg = Kg + (size_t)BHC * NQ * DD;           // bf16 [64][64][2048]
  short* wp = Vtg + (size_t)BHC * DD * NQ;           // bf16 [16][12288] fragment-ordered
  float* biasp = (float*)(wp + 16 * 12288);          // fp32 [16][192] permuted

  wprep_kernel<<<dim3(48, 16), dim3(256), 0, stream>>>(w, bq, wp, biasp);
  proj_kernel<<<dim3(512), dim3(256), 0, stream>>>(x, wp, biasp, Qg, Kg, Vtg);
  attn_kernel<<<dim3(512), dim3(256), 0, stream>>>(Qg, Kg, Vtg, out);
}